// Round 3
// baseline (612.022 us; speedup 1.0000x reference)
//
#include <hip/hip_runtime.h>

#define H    112
#define W    112
#define HW   12544
#define CIN  64
#define COUT 128
#define BATCH 8
#define KK   9
#define OFFC 18
#define EPS  1e-5f
#define TP   32      // pixels per deform block
#define KDIM 576     // CIN*KK
#define KPAD 584     // samp row padding (elements)

typedef unsigned short ushort;
typedef unsigned int uint;
typedef __attribute__((ext_vector_type(8))) short short8;
typedef __attribute__((ext_vector_type(4))) float floatx4;

__device__ __forceinline__ ushort f2bf(float f) {
  uint u = __float_as_uint(f);
  u = (u + 0x7FFFu + ((u >> 16) & 1u)) >> 16;   // RNE
  return (ushort)u;
}

// pack two fp32 -> two bf16 (round-half-up) in one v_perm
__device__ __forceinline__ uint pack_bf2(float f0, float f1) {
  uint u0 = __float_as_uint(f0) + 0x8000u;
  uint u1 = __float_as_uint(f1) + 0x8000u;
  return __builtin_amdgcn_perm(u1, u0, 0x07060302u);
}

// ---------------- K0: transpose x [B][CIN][HW] -> xT [B][HW][CIN] ----------------
__global__ __launch_bounds__(256) void k_transpose_x(
    const float* __restrict__ x, float* __restrict__ xT) {
  __shared__ float tile[64][65];
  int b = blockIdx.y;
  int p0 = blockIdx.x * 64;
  int tid = threadIdx.x;
  int j = tid & 63, cb = tid >> 6;
#pragma unroll
  for (int i = 0; i < 16; ++i) {
    int ci = cb * 16 + i;
    tile[ci][j] = x[((size_t)(b * CIN + ci)) * HW + p0 + j];
  }
  __syncthreads();
  int ci2 = tid & 63;
#pragma unroll
  for (int i = 0; i < 16; ++i) {
    int p = cb * 16 + i;
    xT[((size_t)b * HW + p0 + p) * 64 + ci2] = tile[ci2][p];
  }
}

// ---------------- weight reorders ----------------
// w_r[(kk*64+ci)*18+oc] = w_off[oc][ci][kk]   (fp32, offset conv)
// w_mf[co*576 + kk*64 + ci] = bf16(w_dcn[co][ci][kk])   (MFMA A)
__global__ __launch_bounds__(256) void k_prep_w(
    const float* __restrict__ w_off, const float* __restrict__ w_dcn,
    float* __restrict__ w_r, ushort* __restrict__ w_mf) {
  int i = blockIdx.x * 256 + threadIdx.x;
  if (i < OFFC * KDIM) {
    int oc = i / KDIM, rem = i - oc * KDIM;
    int ci = rem / KK, kk = rem - ci * KK;
    w_r[(kk * 64 + ci) * OFFC + oc] = w_off[i];
  } else if (i < OFFC * KDIM + COUT * KDIM) {
    int jj = i - OFFC * KDIM;
    int co = jj / KDIM, rem = jj - co * KDIM;
    int ci = rem / KK, kk = rem - ci * KK;
    w_mf[co * KDIM + kk * 64 + ci] = f2bf(w_dcn[jj]);
  }
}

// ---------------- K1: offset conv on xT, ci split across wave pairs ----------------
// 256 thd = 4 waves; waves (0,1) and (2,3) pair up: even wave ci 0..31,
// odd wave ci 32..63, each wave covers 64 px. Weights stay wave-uniform (SGPR).
__global__ __launch_bounds__(256) void k_offset_conv(
    const float* __restrict__ xT, const float* __restrict__ w_r,
    const float* __restrict__ bias, float* __restrict__ out) {
  __shared__ float red[2][64][OFFC + 1];
  int b = blockIdx.y;
  int tid = threadIdx.x;
  int wave = tid >> 6, lane = tid & 63;
  int cih = wave & 1;                 // wave-uniform ci half
  int pair = wave >> 1;
  int p = blockIdx.x * 128 + pair * 64 + lane;
  int ho = p / W, wo = p - ho * W;
  float acc[OFFC];
#pragma unroll
  for (int oc = 0; oc < OFFC; ++oc) acc[oc] = 0.f;
  const float* xb = xT + (size_t)b * HW * 64 + cih * 32;
  for (int t = 0; t < 9; ++t) {
    int yy = ho + t / 3 - 1;
    int xx = wo + t % 3 - 1;
    bool valid = (yy >= 0) & (yy < H) & (xx >= 0) & (xx < W);
    const float4* src = (const float4*)(xb + ((size_t)(yy * W + xx) << 6));
    const float* wbase = w_r + (t * 64 + cih * 32) * OFFC;
    if (valid) {
#pragma unroll 2
      for (int cg = 0; cg < 8; ++cg) {
        float4 v = src[cg];
#pragma unroll
        for (int jj = 0; jj < 4; ++jj) {
          float xv = (jj == 0) ? v.x : (jj == 1) ? v.y : (jj == 2) ? v.z : v.w;
          const float* wp = wbase + (cg * 4 + jj) * OFFC;
#pragma unroll
          for (int oc = 0; oc < OFFC; ++oc)
            acc[oc] = fmaf(xv, wp[oc], acc[oc]);
        }
      }
    }
  }
  if (cih) {
#pragma unroll
    for (int oc = 0; oc < OFFC; ++oc) red[pair][lane][oc] = acc[oc];
  }
  __syncthreads();
  if (!cih) {
#pragma unroll
    for (int oc = 0; oc < OFFC; ++oc) {
      float v = acc[oc] + red[pair][lane][oc] + bias[oc];
      out[((size_t)b * OFFC + oc) * HW + p] = v;
    }
  }
}

// ---------------- K3: deformable conv (bf16 MFMA) + fused BN partial stats ----------------
// 512 threads (8 waves), tile 32 px x 128 co; wave w owns co tile w*16.
__global__ __launch_bounds__(512) void k_deform(
    const float* __restrict__ xT, const float* __restrict__ off,
    const ushort* __restrict__ w_mf, float* __restrict__ y,
    float* __restrict__ stats) {
  __shared__ float4 s_w[KK][TP];
  __shared__ int4   s_i[KK][TP];
  __shared__ ushort samp[TP][KPAD];

  int b = blockIdx.y;
  int p0 = blockIdx.x * TP;
  int tid = threadIdx.x;
  const float* xb = xT + (size_t)b * HW * 64;

  // ---- Phase A: bilinear metadata (288 tasks) ----
  if (tid < KK * TP) {
    int kk = tid >> 5;
    int px = tid & 31;
    int p = p0 + px;
    int ho = p / W, wo = p - ho * W;
    float dy = off[((size_t)b * OFFC + 2 * kk) * HW + p];
    float dx = off[((size_t)b * OFFC + 2 * kk + 1) * HW + p];
    float py = dy + (float)(ho - 1 + kk / 3);
    float pxx = dx + (float)(wo - 1 + kk % 3);
    float y0f = floorf(py), x0f = floorf(pxx);
    float wy1 = py - y0f, wx1 = pxx - x0f;
    int y0 = (int)y0f, x0 = (int)x0f;
    int y1 = y0 + 1, x1 = x0 + 1;
    float vy0 = (y0 >= 0 && y0 < H) ? 1.f : 0.f;
    float vy1 = (y1 >= 0 && y1 < H) ? 1.f : 0.f;
    float vx0 = (x0 >= 0 && x0 < W) ? 1.f : 0.f;
    float vx1 = (x1 >= 0 && x1 < W) ? 1.f : 0.f;
    int cy0 = min(max(y0, 0), H - 1), cy1 = min(max(y1, 0), H - 1);
    int cx0 = min(max(x0, 0), W - 1), cx1 = min(max(x1, 0), W - 1);
    s_w[kk][px] = make_float4((1.f - wy1) * (1.f - wx1) * vy0 * vx0,
                              (1.f - wy1) * wx1 * vy0 * vx1,
                              wy1 * (1.f - wx1) * vy1 * vx0,
                              wy1 * wx1 * vy1 * vx1);
    s_i[kk][px] = make_int4((cy0 * W + cx0) << 6, (cy0 * W + cx1) << 6,
                            (cy1 * W + cx0) << 6, (cy1 * W + cx1) << 6);
  }
  __syncthreads();

  // ---- Phase B: sampling. 4608 tasks = 32px x 9kk x 16cig (4 ci each) ----
#pragma unroll
  for (int r = 0; r < 9; ++r) {
    int it = tid + r * 512;
    int px = it / 144;
    int rem = it - px * 144;
    int kk = rem >> 4;
    int cig = rem & 15;
    int ci0 = cig * 4;
    float4 wv = s_w[kk][px];
    int4 iv = s_i[kk][px];
    float4 c0 = *(const float4*)(xb + iv.x + ci0);
    float4 c1 = *(const float4*)(xb + iv.y + ci0);
    float4 c2 = *(const float4*)(xb + iv.z + ci0);
    float4 c3 = *(const float4*)(xb + iv.w + ci0);
    float r0 = wv.x * c0.x + wv.y * c1.x + wv.z * c2.x + wv.w * c3.x;
    float r1 = wv.x * c0.y + wv.y * c1.y + wv.z * c2.y + wv.w * c3.y;
    float r2 = wv.x * c0.z + wv.y * c1.z + wv.z * c2.z + wv.w * c3.z;
    float r3 = wv.x * c0.w + wv.y * c1.w + wv.z * c2.w + wv.w * c3.w;
    uint2 pk = make_uint2(pack_bf2(r0, r1), pack_bf2(r2, r3));
    *(uint2*)&samp[px][kk * 64 + ci0] = pk;
  }
  __syncthreads();

  // ---- Phase C: MFMA GEMM. wave w: co tile 16w..16w+15; 2 N-tiles ----
  int wave = tid >> 6, lane = tid & 63;
  int row16 = lane & 15, quad = lane >> 4;
  int koff = quad * 8;
  int co_base = wave * 16;
  const ushort* wa = w_mf + (size_t)(co_base + row16) * KDIM + koff;
  const ushort* sb0 = &samp[row16][koff];
  const ushort* sb1 = &samp[16 + row16][koff];

  floatx4 acc0 = {0.f, 0.f, 0.f, 0.f}, acc1 = acc0;
#pragma unroll
  for (int ks = 0; ks < KDIM / 32; ++ks) {
    short8 A  = *(const short8*)(wa + ks * 32);
    short8 B0 = *(const short8*)(sb0 + ks * 32);
    short8 B1 = *(const short8*)(sb1 + ks * 32);
    acc0 = __builtin_amdgcn_mfma_f32_16x16x32_bf16(A, B0, acc0, 0, 0, 0);
    acc1 = __builtin_amdgcn_mfma_f32_16x16x32_bf16(A, B1, acc1, 0, 0, 0);
  }

  // ---- epilogue: y store (C/D layout col=lane&15=px, row=quad*4+reg=co) ----
  float* yb = y + (size_t)b * COUT * HW + p0;
#pragma unroll
  for (int reg = 0; reg < 4; ++reg) {
    int r0 = quad * 4 + reg;
    yb[(size_t)(co_base + r0) * HW + row16]      = acc0[reg];
    yb[(size_t)(co_base + r0) * HW + 16 + row16] = acc1[reg];
  }

  // ---- fused BN partial stats: reduce over the 16 px-lanes, atomics ----
#pragma unroll
  for (int reg = 0; reg < 4; ++reg) {
    float s = acc0[reg] + acc1[reg];
    float q = acc0[reg] * acc0[reg] + acc1[reg] * acc1[reg];
#pragma unroll
    for (int m = 1; m < 16; m <<= 1) {
      s += __shfl_xor(s, m, 64);
      q += __shfl_xor(q, m, 64);
    }
    if (row16 == 0) {
      int co = co_base + quad * 4 + reg;
      atomicAdd(&stats[co], s);
      atomicAdd(&stats[COUT + co], q);
    }
  }
}

// ---------------- K5: finalize stats + normalize + ReLU ----------------
__global__ __launch_bounds__(256) void k_norm(const float* __restrict__ y,
                                              const float* __restrict__ stats,
                                              const float* __restrict__ gamma,
                                              const float* __restrict__ beta,
                                              float* __restrict__ out) {
  int i4 = blockIdx.x * 256 + threadIdx.x;
  const int total4 = BATCH * COUT * HW / 4;
  if (i4 >= total4) return;
  size_t i = (size_t)i4 * 4;
  int c = (int)((i / HW) & (COUT - 1));
  const float N = (float)(BATCH * HW);
  float m = stats[c] / N;
  float var = stats[COUT + c] / N - m * m;
  float r = rsqrtf(var + EPS);
  float g = gamma[c], bt = beta[c];
  float4 v = *(const float4*)&y[i];
  v.x = fmaxf(0.f, (v.x - m) * r * g + bt);
  v.y = fmaxf(0.f, (v.y - m) * r * g + bt);
  v.z = fmaxf(0.f, (v.z - m) * r * g + bt);
  v.w = fmaxf(0.f, (v.w - m) * r * g + bt);
  *(float4*)&out[i] = v;
}

extern "C" void kernel_launch(void* const* d_in, const int* in_sizes, int n_in,
                              void* d_out, int out_size, void* d_ws, size_t ws_size,
                              hipStream_t stream) {
  const float* x     = (const float*)d_in[0];
  const float* w_off = (const float*)d_in[1];
  const float* b_off = (const float*)d_in[2];
  const float* w_dcn = (const float*)d_in[3];
  // d_in[4] = b_dcn: cancels exactly through batch-norm
  const float* gamma = (const float*)d_in[5];
  const float* beta  = (const float*)d_in[6];
  float* out = (float*)d_out;

  float* ws = (float*)d_ws;
  float*  xT      = ws;                               // 6,422,528 floats
  float*  off_buf = xT + 6422528;                     // 1,806,336
  float*  w_r     = off_buf + 1806336;                //    10,368
  ushort* w_mf    = (ushort*)(w_r + 10368);           //    73,728 ushorts
  float*  y       = w_r + 10368 + 36864;              // 12,845,056
  float*  stats   = y + 12845056;                     //       256

  hipMemsetAsync(stats, 0, 256 * sizeof(float), stream);
  k_transpose_x<<<dim3(HW / 64, BATCH), 256, 0, stream>>>(x, xT);
  k_prep_w<<<(OFFC * KDIM + COUT * KDIM + 255) / 256, 256, 0, stream>>>(w_off, w_dcn, w_r, w_mf);
  k_offset_conv<<<dim3(HW / 128, BATCH), 256, 0, stream>>>(xT, w_r, b_off, off_buf);
  k_deform<<<dim3(HW / TP, BATCH), 512, 0, stream>>>(xT, off_buf, w_mf, y, stats);
  k_norm<<<(BATCH * COUT * HW / 4 + 255) / 256, 256, 0, stream>>>(y, stats, gamma, beta, out);
}

// Round 4
// 243.254 us; speedup vs baseline: 2.5160x; 2.5160x over previous
//
#include <hip/hip_runtime.h>

#define H    112
#define W    112
#define HW   12544
#define CIN  64
#define COUT 128
#define BATCH 8
#define KK   9
#define OFFC 18
#define EPS  1e-5f
#define TP   32      // pixels per deform block
#define KDIM 576     // CIN*KK
#define KPAD 584     // samp row padding (elements)

typedef unsigned short ushort;
typedef unsigned int uint;
typedef __attribute__((ext_vector_type(8))) short short8;
typedef __attribute__((ext_vector_type(8))) ushort ushort8;
typedef __attribute__((ext_vector_type(4))) float floatx4;

__device__ __forceinline__ ushort f2bf(float f) {
  uint u = __float_as_uint(f);
  u = (u + 0x7FFFu + ((u >> 16) & 1u)) >> 16;   // RNE
  return (ushort)u;
}

// pack two fp32 -> two bf16 (round-half-up) in one v_perm
__device__ __forceinline__ uint pack_bf2(float f0, float f1) {
  uint u0 = __float_as_uint(f0) + 0x8000u;
  uint u1 = __float_as_uint(f1) + 0x8000u;
  return __builtin_amdgcn_perm(u1, u0, 0x07060302u);
}

__device__ __forceinline__ float bf2f(ushort u) {
  return __uint_as_float(((uint)u) << 16);
}

// ---------------- K0: transpose x [B][CIN][HW] -> xTb [B][HW][CIN] bf16 ----------------
__global__ __launch_bounds__(256) void k_transpose_x(
    const float* __restrict__ x, ushort* __restrict__ xTb) {
  __shared__ float tile[64][65];
  int b = blockIdx.y;
  int p0 = blockIdx.x * 64;
  int tid = threadIdx.x;
  int j = tid & 63, cb = tid >> 6;
#pragma unroll
  for (int i = 0; i < 16; ++i) {
    int ci = cb * 16 + i;
    tile[ci][j] = x[((size_t)(b * CIN + ci)) * HW + p0 + j];
  }
  __syncthreads();
  // write: thread -> (px = tid>>2, ciq = tid&3), 16 ci as 2 ushort8
  int px = tid >> 2, ciq = tid & 3;
  uint pk[4];
#pragma unroll
  for (int g = 0; g < 4; ++g) {
    int ci = ciq * 16 + g * 4;
    pk[g] = 0;  // silence unused warning pattern
    uint lo = pack_bf2(tile[ci + 0][px], tile[ci + 1][px]);
    uint hi = pack_bf2(tile[ci + 2][px], tile[ci + 3][px]);
    ((uint2*)pk)[g >> 1] = make_uint2(0, 0);  // placeholder, overwritten below
    pk[g] = lo;  // not used; real store below
    // store 8 bytes directly
    *(uint2*)&xTb[((size_t)b * HW + p0 + px) * 64 + ci] = make_uint2(lo, hi);
  }
}

// ---------------- weight reorders ----------------
// w_r[(kk*64+ci)*18+oc] = w_off[oc][ci][kk]   (fp32, offset conv)
// w_mf[co*576 + kk*64 + ci] = bf16(w_dcn[co][ci][kk])   (MFMA A)
__global__ __launch_bounds__(256) void k_prep_w(
    const float* __restrict__ w_off, const float* __restrict__ w_dcn,
    float* __restrict__ w_r, ushort* __restrict__ w_mf) {
  int i = blockIdx.x * 256 + threadIdx.x;
  if (i < OFFC * KDIM) {
    int oc = i / KDIM, rem = i - oc * KDIM;
    int ci = rem / KK, kk = rem - ci * KK;
    w_r[(kk * 64 + ci) * OFFC + oc] = w_off[i];
  } else if (i < OFFC * KDIM + COUT * KDIM) {
    int jj = i - OFFC * KDIM;
    int co = jj / KDIM, rem = jj - co * KDIM;
    int ci = rem / KK, kk = rem - ci * KK;
    w_mf[co * KDIM + kk * 64 + ci] = f2bf(w_dcn[jj]);
  }
}

// ---------------- K1: offset conv on xTb (bf16 x, fp32 weights/acc) ----------------
// 1 thread/pixel; grid (49, B). Per tap: 8 ushort8 channel loads + 64*18 FMA
// with wave-uniform weights (scalar loads from w_r).
__global__ __launch_bounds__(256) void k_offset_conv(
    const ushort* __restrict__ xTb, const float* __restrict__ w_r,
    const float* __restrict__ bias, float* __restrict__ out) {
  int b = blockIdx.y;
  int p = blockIdx.x * 256 + threadIdx.x;   // 49*256 == HW exactly
  int ho = p / W, wo = p - ho * W;
  float acc[OFFC];
#pragma unroll
  for (int oc = 0; oc < OFFC; ++oc) acc[oc] = bias[oc];
  const ushort* xb = xTb + (size_t)b * HW * 64;
  for (int t = 0; t < 9; ++t) {
    int yy = ho + t / 3 - 1;
    int xx = wo + t % 3 - 1;
    bool valid = (yy >= 0) & (yy < H) & (xx >= 0) & (xx < W);
    const ushort8* src = (const ushort8*)(xb + ((size_t)(yy * W + xx) << 6));
    const float* wbase = w_r + t * 64 * OFFC;
    if (valid) {
#pragma unroll 2
      for (int cg = 0; cg < 8; ++cg) {
        ushort8 v = src[cg];
#pragma unroll
        for (int jj = 0; jj < 8; ++jj) {
          float xv = bf2f(v[jj]);
          const float* wp = wbase + (cg * 8 + jj) * OFFC;
#pragma unroll
          for (int oc = 0; oc < OFFC; ++oc)
            acc[oc] = fmaf(xv, wp[oc], acc[oc]);
        }
      }
    }
  }
#pragma unroll
  for (int oc = 0; oc < OFFC; ++oc)
    out[((size_t)b * OFFC + oc) * HW + p] = acc[oc];
}

// ---------------- K3: deformable conv via bf16 MFMA -> y [B][COUT][HW] ----------------
// 256 threads (4 waves), tile 32 px x 128 co. Round-2 structure, bf16 gathers.
__global__ __launch_bounds__(256) void k_deform(
    const ushort* __restrict__ xTb, const float* __restrict__ off,
    const ushort* __restrict__ w_mf, float* __restrict__ y) {
  __shared__ float4 s_w[KK][TP];
  __shared__ int4   s_i[KK][TP];
  __shared__ ushort samp[TP][KPAD];

  int b = blockIdx.y;
  int p0 = blockIdx.x * TP;
  int tid = threadIdx.x;
  const ushort* xb = xTb + (size_t)b * HW * 64;

  // ---- Phase A: bilinear metadata (288 tasks) ----
  for (int it = tid; it < KK * TP; it += 256) {
    int kk = it >> 5;
    int px = it & 31;
    int p = p0 + px;
    int ho = p / W, wo = p - ho * W;
    float dy = off[((size_t)b * OFFC + 2 * kk) * HW + p];
    float dx = off[((size_t)b * OFFC + 2 * kk + 1) * HW + p];
    float py = dy + (float)(ho - 1 + kk / 3);
    float pxx = dx + (float)(wo - 1 + kk % 3);
    float y0f = floorf(py), x0f = floorf(pxx);
    float wy1 = py - y0f, wx1 = pxx - x0f;
    int y0 = (int)y0f, x0 = (int)x0f;
    int y1 = y0 + 1, x1 = x0 + 1;
    float vy0 = (y0 >= 0 && y0 < H) ? 1.f : 0.f;
    float vy1 = (y1 >= 0 && y1 < H) ? 1.f : 0.f;
    float vx0 = (x0 >= 0 && x0 < W) ? 1.f : 0.f;
    float vx1 = (x1 >= 0 && x1 < W) ? 1.f : 0.f;
    int cy0 = min(max(y0, 0), H - 1), cy1 = min(max(y1, 0), H - 1);
    int cx0 = min(max(x0, 0), W - 1), cx1 = min(max(x1, 0), W - 1);
    s_w[kk][px] = make_float4((1.f - wy1) * (1.f - wx1) * vy0 * vx0,
                              (1.f - wy1) * wx1 * vy0 * vx1,
                              wy1 * (1.f - wx1) * vy1 * vx0,
                              wy1 * wx1 * vy1 * vx1);
    s_i[kk][px] = make_int4((cy0 * W + cx0) << 6, (cy0 * W + cx1) << 6,
                            (cy1 * W + cx0) << 6, (cy1 * W + cx1) << 6);
  }
  __syncthreads();

  // ---- Phase B: sampling. 2304 tasks = 32px x 9kk x 8cig (8 ci each) ----
#pragma unroll
  for (int r = 0; r < 9; ++r) {
    int it = tid + r * 256;
    int px = it / 72;
    int rem = it - px * 72;
    int kk = rem >> 3;
    int cig = rem & 7;
    int ci0 = cig * 8;
    float4 wv = s_w[kk][px];
    int4 iv = s_i[kk][px];
    ushort8 c0 = *(const ushort8*)(xb + iv.x + ci0);
    ushort8 c1 = *(const ushort8*)(xb + iv.y + ci0);
    ushort8 c2 = *(const ushort8*)(xb + iv.z + ci0);
    ushort8 c3 = *(const ushort8*)(xb + iv.w + ci0);
    uint pk[4];
#pragma unroll
    for (int g = 0; g < 4; ++g) {
      float r0 = wv.x * bf2f(c0[2 * g])     + wv.y * bf2f(c1[2 * g]) +
                 wv.z * bf2f(c2[2 * g])     + wv.w * bf2f(c3[2 * g]);
      float r1 = wv.x * bf2f(c0[2 * g + 1]) + wv.y * bf2f(c1[2 * g + 1]) +
                 wv.z * bf2f(c2[2 * g + 1]) + wv.w * bf2f(c3[2 * g + 1]);
      pk[g] = pack_bf2(r0, r1);
    }
    *(uint4*)&samp[px][kk * 64 + ci0] = make_uint4(pk[0], pk[1], pk[2], pk[3]);
  }
  __syncthreads();

  // ---- Phase C: MFMA GEMM. wave w: co block 32w..32w+31; 2 M-tiles x 2 N-tiles ----
  int wave = tid >> 6, lane = tid & 63;
  int row16 = lane & 15, quad = lane >> 4;
  int koff = quad * 8;
  int co_base = wave * 32;
  const ushort* wa0 = w_mf + (size_t)(co_base + row16) * KDIM + koff;
  const ushort* wa1 = w_mf + (size_t)(co_base + 16 + row16) * KDIM + koff;
  const ushort* sb0 = &samp[row16][koff];
  const ushort* sb1 = &samp[16 + row16][koff];

  floatx4 acc00 = {0.f, 0.f, 0.f, 0.f}, acc01 = acc00, acc10 = acc00, acc11 = acc00;
#pragma unroll
  for (int ks = 0; ks < KDIM / 32; ++ks) {
    short8 A0 = *(const short8*)(wa0 + ks * 32);
    short8 A1 = *(const short8*)(wa1 + ks * 32);
    short8 B0 = *(const short8*)(sb0 + ks * 32);
    short8 B1 = *(const short8*)(sb1 + ks * 32);
    acc00 = __builtin_amdgcn_mfma_f32_16x16x32_bf16(A0, B0, acc00, 0, 0, 0);
    acc01 = __builtin_amdgcn_mfma_f32_16x16x32_bf16(A0, B1, acc01, 0, 0, 0);
    acc10 = __builtin_amdgcn_mfma_f32_16x16x32_bf16(A1, B0, acc10, 0, 0, 0);
    acc11 = __builtin_amdgcn_mfma_f32_16x16x32_bf16(A1, B1, acc11, 0, 0, 0);
  }

  // ---- epilogue: C/D layout col=lane&15 (px), row=quad*4+reg (co) ----
  float* yb = y + (size_t)b * COUT * HW + p0;
#pragma unroll
  for (int reg = 0; reg < 4; ++reg) {
    int r0 = quad * 4 + reg;
    yb[(size_t)(co_base + r0) * HW + row16]      = acc00[reg];
    yb[(size_t)(co_base + r0) * HW + 16 + row16] = acc01[reg];
    yb[(size_t)(co_base + 16 + r0) * HW + row16]      = acc10[reg];
    yb[(size_t)(co_base + 16 + r0) * HW + 16 + row16] = acc11[reg];
  }
}

// ---------------- K4: per-channel partial stats (512 blocks, 2K atomics total) ----------------
__global__ __launch_bounds__(256) void k_stats(const float* __restrict__ y,
                                               float* __restrict__ stats) {
  int c = blockIdx.x & 127;
  int half = blockIdx.x >> 7;     // 0..3, 2 batches each
  int tid = threadIdx.x;
  float s = 0.f, s2 = 0.f;
#pragma unroll
  for (int bb = 0; bb < 2; ++bb) {
    int b = half * 2 + bb;
    const float4* yp = (const float4*)(y + ((size_t)b * COUT + c) * HW);
    for (int p = tid; p < HW / 4; p += 256) {
      float4 v = yp[p];
      s += v.x + v.y + v.z + v.w;
      s2 += v.x * v.x + v.y * v.y + v.z * v.z + v.w * v.w;
    }
  }
#pragma unroll
  for (int o = 32; o > 0; o >>= 1) {
    s += __shfl_down(s, o, 64);
    s2 += __shfl_down(s2, o, 64);
  }
  __shared__ float ls[4], ls2[4];
  int lane = tid & 63, wid = tid >> 6;
  if (lane == 0) { ls[wid] = s; ls2[wid] = s2; }
  __syncthreads();
  if (tid == 0) {
    atomicAdd(&stats[c], ls[0] + ls[1] + ls[2] + ls[3]);
    atomicAdd(&stats[COUT + c], ls2[0] + ls2[1] + ls2[2] + ls2[3]);
  }
}

// ---------------- K5: finalize stats + normalize + ReLU ----------------
__global__ __launch_bounds__(256) void k_norm(const float* __restrict__ y,
                                              const float* __restrict__ stats,
                                              const float* __restrict__ gamma,
                                              const float* __restrict__ beta,
                                              float* __restrict__ out) {
  int i4 = blockIdx.x * 256 + threadIdx.x;
  const int total4 = BATCH * COUT * HW / 4;
  if (i4 >= total4) return;
  size_t i = (size_t)i4 * 4;
  int c = (int)((i / HW) & (COUT - 1));
  const float N = (float)(BATCH * HW);
  float m = stats[c] / N;
  float var = stats[COUT + c] / N - m * m;
  float r = rsqrtf(var + EPS);
  float g = gamma[c], bt = beta[c];
  float4 v = *(const float4*)&y[i];
  v.x = fmaxf(0.f, (v.x - m) * r * g + bt);
  v.y = fmaxf(0.f, (v.y - m) * r * g + bt);
  v.z = fmaxf(0.f, (v.z - m) * r * g + bt);
  v.w = fmaxf(0.f, (v.w - m) * r * g + bt);
  *(float4*)&out[i] = v;
}

extern "C" void kernel_launch(void* const* d_in, const int* in_sizes, int n_in,
                              void* d_out, int out_size, void* d_ws, size_t ws_size,
                              hipStream_t stream) {
  const float* x     = (const float*)d_in[0];
  const float* w_off = (const float*)d_in[1];
  const float* b_off = (const float*)d_in[2];
  const float* w_dcn = (const float*)d_in[3];
  // d_in[4] = b_dcn: cancels exactly through batch-norm
  const float* gamma = (const float*)d_in[5];
  const float* beta  = (const float*)d_in[6];
  float* out = (float*)d_out;

  float* ws = (float*)d_ws;
  float*  off_buf = ws;                               //  1,806,336 floats
  float*  w_r     = off_buf + 1806336;                //     10,368
  float*  y       = w_r + 10368;                      // 12,845,056
  float*  stats   = y + 12845056;                     //        256
  ushort* xTb     = (ushort*)(stats + 256);           //  6,422,528 ushorts
  ushort* w_mf    = xTb + 6422528;                    //     73,728 ushorts
  // total ~71.7 MB

  hipMemsetAsync(stats, 0, 256 * sizeof(float), stream);
  k_transpose_x<<<dim3(HW / 64, BATCH), 256, 0, stream>>>(x, xTb);
  k_prep_w<<<(OFFC * KDIM + COUT * KDIM + 255) / 256, 256, 0, stream>>>(w_off, w_dcn, w_r, w_mf);
  k_offset_conv<<<dim3(HW / 256, BATCH), 256, 0, stream>>>(xTb, w_r, b_off, off_buf);
  k_deform<<<dim3(HW / TP, BATCH), 256, 0, stream>>>(xTb, off_buf, w_mf, y);
  k_stats<<<512, 256, 0, stream>>>(y, stats);
  k_norm<<<(BATCH * COUT * HW / 4 + 255) / 256, 256, 0, stream>>>(y, stats, gamma, beta, out);
}

// Round 5
// 236.519 us; speedup vs baseline: 2.5876x; 1.0285x over previous
//
#include <hip/hip_runtime.h>

#define H    112
#define W    112
#define HW   12544
#define CIN  64
#define COUT 128
#define BATCH 8
#define KK   9
#define OFFC 18
#define EPS  1e-5f
#define TP   32      // pixels per deform block
#define KDIM 576     // CIN*KK
#define KHALF 288    // K split in two passes
#define KPAD2 296    // samp row stride (elements): 148 words % 32 = 20 -> 2-way max

typedef unsigned short ushort;
typedef unsigned int uint;
typedef __attribute__((ext_vector_type(8))) short short8;
typedef __attribute__((ext_vector_type(8))) ushort ushort8;
typedef __attribute__((ext_vector_type(4))) float floatx4;

__device__ __forceinline__ ushort f2bf(float f) {
  uint u = __float_as_uint(f);
  u = (u + 0x7FFFu + ((u >> 16) & 1u)) >> 16;   // RNE
  return (ushort)u;
}

// pack two fp32 -> two bf16 (round-half-up) in one v_perm
__device__ __forceinline__ uint pack_bf2(float f0, float f1) {
  uint u0 = __float_as_uint(f0) + 0x8000u;
  uint u1 = __float_as_uint(f1) + 0x8000u;
  return __builtin_amdgcn_perm(u1, u0, 0x07060302u);
}

__device__ __forceinline__ float bf2f(ushort u) {
  return __uint_as_float(((uint)u) << 16);
}

// ---------------- K0: transpose x [B][CIN][HW] -> xTb [B][HW][CIN] bf16 ----------------
__global__ __launch_bounds__(256) void k_transpose_x(
    const float* __restrict__ x, ushort* __restrict__ xTb) {
  __shared__ float tile[64][65];
  int b = blockIdx.y;
  int p0 = blockIdx.x * 64;
  int tid = threadIdx.x;
  int j = tid & 63, cb = tid >> 6;
#pragma unroll
  for (int i = 0; i < 16; ++i) {
    int ci = cb * 16 + i;
    tile[ci][j] = x[((size_t)(b * CIN + ci)) * HW + p0 + j];
  }
  __syncthreads();
  int px = tid >> 2, ciq = tid & 3;
#pragma unroll
  for (int g = 0; g < 4; ++g) {
    int ci = ciq * 16 + g * 4;
    uint lo = pack_bf2(tile[ci + 0][px], tile[ci + 1][px]);
    uint hi = pack_bf2(tile[ci + 2][px], tile[ci + 3][px]);
    *(uint2*)&xTb[((size_t)b * HW + p0 + px) * 64 + ci] = make_uint2(lo, hi);
  }
}

// ---------------- weight prep ----------------
// w_offT[oc][k], k = kk*64+ci, oc padded to 32 (zeros) -- bf16 MFMA A for offset conv
// w_mf[co][h*288 + kk*32 + cil], ci = h*32+cil            -- bf16 MFMA A for deform
__global__ __launch_bounds__(256) void k_prep_w(
    const float* __restrict__ w_off, const float* __restrict__ w_dcn,
    ushort* __restrict__ w_offT, ushort* __restrict__ w_mf) {
  int i = blockIdx.x * 256 + threadIdx.x;
  if (i < 32 * KDIM) {
    int oc = i / KDIM, k = i - oc * KDIM;
    int kk = k >> 6, ci = k & 63;
    float v = (oc < OFFC) ? w_off[(oc * CIN + ci) * KK + kk] : 0.f;
    w_offT[i] = f2bf(v);
  } else if (i < 32 * KDIM + COUT * KDIM) {
    int jj = i - 32 * KDIM;
    int co = jj / KDIM, k = jj - co * KDIM;
    int h = k / KHALF, r = k - h * KHALF;
    int kk = r >> 5, cil = r & 31;
    int ci = h * 32 + cil;
    w_mf[jj] = f2bf(w_dcn[(co * CIN + ci) * KK + kk]);
  }
}

// ---------------- K1: offset conv as register-resident bf16 MFMA ----------------
// 4 waves/block, each wave: 16 px x 32 oc (18 real). B-frags built directly
// from xTb 3x3 neighborhood (zero-masked borders) -- no LDS, no barriers.
__global__ __launch_bounds__(256) void k_offset_conv(
    const ushort* __restrict__ xTb, const ushort* __restrict__ w_offT,
    const float* __restrict__ bias, float* __restrict__ out) {
  int b = blockIdx.y;
  int wave = threadIdx.x >> 6, lane = threadIdx.x & 63;
  int row16 = lane & 15, quad = lane >> 4;
  int p = blockIdx.x * 64 + wave * 16 + row16;
  int ho = p / W, wo = p - ho * W;
  const ushort* xb = xTb + (size_t)b * HW * 64;

  short8 Bf[18];
#pragma unroll
  for (int ks = 0; ks < 18; ++ks) {
    int kk = ks >> 1;
    int ci0 = (ks & 1) * 32 + quad * 8;
    int kh = kk / 3, kw = kk - kh * 3;
    int yy = ho + kh - 1, xx = wo + kw - 1;
    bool valid = (yy >= 0) & (yy < H) & (xx >= 0) & (xx < W);
    short8 v = {0, 0, 0, 0, 0, 0, 0, 0};
    if (valid) v = *(const short8*)(xb + ((size_t)(yy * W + xx) << 6) + ci0);
    Bf[ks] = v;
  }
  floatx4 acc0 = {0.f, 0.f, 0.f, 0.f}, acc1 = acc0;
  const ushort* wa0 = w_offT + row16 * KDIM + quad * 8;
  const ushort* wa1 = w_offT + (16 + row16) * KDIM + quad * 8;
#pragma unroll
  for (int ks = 0; ks < 18; ++ks) {
    short8 A0 = *(const short8*)(wa0 + ks * 32);
    short8 A1 = *(const short8*)(wa1 + ks * 32);
    acc0 = __builtin_amdgcn_mfma_f32_16x16x32_bf16(A0, Bf[ks], acc0, 0, 0, 0);
    acc1 = __builtin_amdgcn_mfma_f32_16x16x32_bf16(A1, Bf[ks], acc1, 0, 0, 0);
  }
  // C/D: col=lane&15 (px), row=quad*4+reg (oc)
  float* ob = out + (size_t)b * OFFC * HW;
#pragma unroll
  for (int reg = 0; reg < 4; ++reg) {
    int oc = quad * 4 + reg;
    ob[(size_t)oc * HW + p] = acc0[reg] + bias[oc];
    int oc1 = 16 + oc;
    if (oc1 < OFFC) ob[(size_t)oc1 * HW + p] = acc1[reg] + bias[oc1];
  }
}

// ---------------- K3: deformable conv, K-split bf16 MFMA -> y [B][COUT][HW] ----------------
// 256 threads (4 waves), tile 32 px x 128 co. LDS 27.5 KB -> 5 blocks/CU.
__global__ __launch_bounds__(256) void k_deform(
    const ushort* __restrict__ xTb, const float* __restrict__ off,
    const ushort* __restrict__ w_mf, float* __restrict__ y) {
  __shared__ float4 s_w[KK][TP];
  __shared__ int4   s_i[KK][TP];
  __shared__ ushort samp[TP][KPAD2];

  int b = blockIdx.y;
  int p0 = blockIdx.x * TP;
  int tid = threadIdx.x;
  const ushort* xb = xTb + (size_t)b * HW * 64;

  // ---- Phase A: bilinear metadata (288 tasks) ----
  for (int it = tid; it < KK * TP; it += 256) {
    int kk = it >> 5;
    int px = it & 31;
    int p = p0 + px;
    int ho = p / W, wo = p - ho * W;
    float dy = off[((size_t)b * OFFC + 2 * kk) * HW + p];
    float dx = off[((size_t)b * OFFC + 2 * kk + 1) * HW + p];
    float py = dy + (float)(ho - 1 + kk / 3);
    float pxx = dx + (float)(wo - 1 + kk % 3);
    float y0f = floorf(py), x0f = floorf(pxx);
    float wy1 = py - y0f, wx1 = pxx - x0f;
    int y0 = (int)y0f, x0 = (int)x0f;
    int y1 = y0 + 1, x1 = x0 + 1;
    float vy0 = (y0 >= 0 && y0 < H) ? 1.f : 0.f;
    float vy1 = (y1 >= 0 && y1 < H) ? 1.f : 0.f;
    float vx0 = (x0 >= 0 && x0 < W) ? 1.f : 0.f;
    float vx1 = (x1 >= 0 && x1 < W) ? 1.f : 0.f;
    int cy0 = min(max(y0, 0), H - 1), cy1 = min(max(y1, 0), H - 1);
    int cx0 = min(max(x0, 0), W - 1), cx1 = min(max(x1, 0), W - 1);
    s_w[kk][px] = make_float4((1.f - wy1) * (1.f - wx1) * vy0 * vx0,
                              (1.f - wy1) * wx1 * vy0 * vx1,
                              wy1 * (1.f - wx1) * vy1 * vx0,
                              wy1 * wx1 * vy1 * vx1);
    s_i[kk][px] = make_int4((cy0 * W + cx0) << 6, (cy0 * W + cx1) << 6,
                            (cy1 * W + cx0) << 6, (cy1 * W + cx1) << 6);
  }
  __syncthreads();

  int wave = tid >> 6, lane = tid & 63;
  int row16 = lane & 15, quad = lane >> 4;
  int koff = quad * 8;
  int co_base = wave * 32;
  const ushort* wa0 = w_mf + (size_t)(co_base + row16) * KDIM + koff;
  const ushort* wa1 = w_mf + (size_t)(co_base + 16 + row16) * KDIM + koff;

  floatx4 acc00 = {0.f, 0.f, 0.f, 0.f}, acc01 = acc00, acc10 = acc00, acc11 = acc00;

  for (int h = 0; h < 2; ++h) {
    // ---- gather half h: 1152 tasks = 32px x 9kk x 4cig (8 ci each) ----
#pragma unroll
    for (int r = 0; r < 5; ++r) {
      int it = tid + r * 256;
      if (it < 1152) {
        int px = it / 36;
        int rem = it - px * 36;
        int kk = rem >> 2;
        int cig = rem & 3;
        int cil0 = cig * 8;
        int cio = h * 32 + cil0;
        float4 wv = s_w[kk][px];
        int4 iv = s_i[kk][px];
        ushort8 c0 = *(const ushort8*)(xb + iv.x + cio);
        ushort8 c1 = *(const ushort8*)(xb + iv.y + cio);
        ushort8 c2 = *(const ushort8*)(xb + iv.z + cio);
        ushort8 c3 = *(const ushort8*)(xb + iv.w + cio);
        uint pk[4];
#pragma unroll
        for (int g = 0; g < 4; ++g) {
          float r0 = wv.x * bf2f(c0[2 * g])     + wv.y * bf2f(c1[2 * g]) +
                     wv.z * bf2f(c2[2 * g])     + wv.w * bf2f(c3[2 * g]);
          float r1 = wv.x * bf2f(c0[2 * g + 1]) + wv.y * bf2f(c1[2 * g + 1]) +
                     wv.z * bf2f(c2[2 * g + 1]) + wv.w * bf2f(c3[2 * g + 1]);
          pk[g] = pack_bf2(r0, r1);
        }
        *(uint4*)&samp[px][kk * 32 + cil0] = make_uint4(pk[0], pk[1], pk[2], pk[3]);
      }
    }
    __syncthreads();

    // ---- MFMA over this K-half: 9 ks steps x 4 MFMA ----
    const ushort* sb0 = &samp[row16][koff];
    const ushort* sb1 = &samp[16 + row16][koff];
    const ushort* a0 = wa0 + h * KHALF;
    const ushort* a1 = wa1 + h * KHALF;
#pragma unroll
    for (int ks = 0; ks < 9; ++ks) {
      short8 A0 = *(const short8*)(a0 + ks * 32);
      short8 A1 = *(const short8*)(a1 + ks * 32);
      short8 B0 = *(const short8*)(sb0 + ks * 32);
      short8 B1 = *(const short8*)(sb1 + ks * 32);
      acc00 = __builtin_amdgcn_mfma_f32_16x16x32_bf16(A0, B0, acc00, 0, 0, 0);
      acc01 = __builtin_amdgcn_mfma_f32_16x16x32_bf16(A0, B1, acc01, 0, 0, 0);
      acc10 = __builtin_amdgcn_mfma_f32_16x16x32_bf16(A1, B0, acc10, 0, 0, 0);
      acc11 = __builtin_amdgcn_mfma_f32_16x16x32_bf16(A1, B1, acc11, 0, 0, 0);
    }
    if (h == 0) __syncthreads();   // samp reused by half 1
  }

  // ---- epilogue: C/D layout col=lane&15 (px), row=quad*4+reg (co) ----
  float* yb = y + (size_t)b * COUT * HW + p0;
#pragma unroll
  for (int reg = 0; reg < 4; ++reg) {
    int r0 = quad * 4 + reg;
    yb[(size_t)(co_base + r0) * HW + row16]      = acc00[reg];
    yb[(size_t)(co_base + r0) * HW + 16 + row16] = acc01[reg];
    yb[(size_t)(co_base + 16 + r0) * HW + row16]      = acc10[reg];
    yb[(size_t)(co_base + 16 + r0) * HW + 16 + row16] = acc11[reg];
  }
}

// ---------------- K4: per-channel partial stats (512 blocks, 2K atomics total) ----------------
__global__ __launch_bounds__(256) void k_stats(const float* __restrict__ y,
                                               float* __restrict__ stats) {
  int c = blockIdx.x & 127;
  int half = blockIdx.x >> 7;
  int tid = threadIdx.x;
  float s = 0.f, s2 = 0.f;
#pragma unroll
  for (int bb = 0; bb < 2; ++bb) {
    int b = half * 2 + bb;
    const float4* yp = (const float4*)(y + ((size_t)b * COUT + c) * HW);
    for (int p = tid; p < HW / 4; p += 256) {
      float4 v = yp[p];
      s += v.x + v.y + v.z + v.w;
      s2 += v.x * v.x + v.y * v.y + v.z * v.z + v.w * v.w;
    }
  }
#pragma unroll
  for (int o = 32; o > 0; o >>= 1) {
    s += __shfl_down(s, o, 64);
    s2 += __shfl_down(s2, o, 64);
  }
  __shared__ float ls[4], ls2[4];
  int lane = tid & 63, wid = tid >> 6;
  if (lane == 0) { ls[wid] = s; ls2[wid] = s2; }
  __syncthreads();
  if (tid == 0) {
    atomicAdd(&stats[c], ls[0] + ls[1] + ls[2] + ls[3]);
    atomicAdd(&stats[COUT + c], ls2[0] + ls2[1] + ls2[2] + ls2[3]);
  }
}

// ---------------- K5: finalize stats + normalize + ReLU ----------------
__global__ __launch_bounds__(256) void k_norm(const float* __restrict__ y,
                                              const float* __restrict__ stats,
                                              const float* __restrict__ gamma,
                                              const float* __restrict__ beta,
                                              float* __restrict__ out) {
  int i4 = blockIdx.x * 256 + threadIdx.x;
  const int total4 = BATCH * COUT * HW / 4;
  if (i4 >= total4) return;
  size_t i = (size_t)i4 * 4;
  int c = (int)((i / HW) & (COUT - 1));
  const float N = (float)(BATCH * HW);
  float m = stats[c] / N;
  float var = stats[COUT + c] / N - m * m;
  float r = rsqrtf(var + EPS);
  float g = gamma[c], bt = beta[c];
  float4 v = *(const float4*)&y[i];
  v.x = fmaxf(0.f, (v.x - m) * r * g + bt);
  v.y = fmaxf(0.f, (v.y - m) * r * g + bt);
  v.z = fmaxf(0.f, (v.z - m) * r * g + bt);
  v.w = fmaxf(0.f, (v.w - m) * r * g + bt);
  *(float4*)&out[i] = v;
}

extern "C" void kernel_launch(void* const* d_in, const int* in_sizes, int n_in,
                              void* d_out, int out_size, void* d_ws, size_t ws_size,
                              hipStream_t stream) {
  const float* x     = (const float*)d_in[0];
  const float* w_off = (const float*)d_in[1];
  const float* b_off = (const float*)d_in[2];
  const float* w_dcn = (const float*)d_in[3];
  // d_in[4] = b_dcn: cancels exactly through batch-norm
  const float* gamma = (const float*)d_in[5];
  const float* beta  = (const float*)d_in[6];
  float* out = (float*)d_out;

  float* ws = (float*)d_ws;
  float*  off_buf = ws;                               //  1,806,336 floats
  float*  y       = off_buf + 1806336;                // 12,845,056
  float*  stats   = y + 12845056;                     //        256
  ushort* xTb     = (ushort*)(stats + 256);           //  6,422,528 ushorts
  ushort* w_mf    = xTb + 6422528;                    //     73,728 ushorts
  ushort* w_offT  = w_mf + 73728;                     //     18,432 ushorts

  hipMemsetAsync(stats, 0, 256 * sizeof(float), stream);
  k_transpose_x<<<dim3(HW / 64, BATCH), 256, 0, stream>>>(x, xTb);
  k_prep_w<<<(32 * KDIM + COUT * KDIM + 255) / 256, 256, 0, stream>>>(w_off, w_dcn, w_offT, w_mf);
  k_offset_conv<<<dim3(HW / 64, BATCH), 256, 0, stream>>>(xTb, w_offT, b_off, off_buf);
  k_deform<<<dim3(HW / TP, BATCH), 256, 0, stream>>>(xTb, off_buf, w_mf, y);
  k_stats<<<512, 256, 0, stream>>>(y, stats);
  k_norm<<<(BATCH * COUT * HW / 4 + 255) / 256, 256, 0, stream>>>(y, stats, gamma, beta, out);
}

// Round 6
// 227.632 us; speedup vs baseline: 2.6886x; 1.0390x over previous
//
#include <hip/hip_runtime.h>

#define H    112
#define W    112
#define HW   12544
#define CIN  64
#define COUT 128
#define BATCH 8
#define KK   9
#define OFFC 18
#define EPS  1e-5f
#define TP   32      // pixels per deform block
#define KDIM 576     // CIN*KK
#define KHALF 288    // K split in two passes
#define KPAD2 296    // samp row stride (elements): 148 words % 32 = 20 -> 2-way max
#define NB   3136    // deform grid size (HW/TP * BATCH)

typedef unsigned short ushort;
typedef unsigned int uint;
typedef __attribute__((ext_vector_type(8))) short short8;
typedef __attribute__((ext_vector_type(8))) ushort ushort8;
typedef __attribute__((ext_vector_type(4))) float floatx4;

__device__ __forceinline__ ushort f2bf(float f) {
  uint u = __float_as_uint(f);
  u = (u + 0x7FFFu + ((u >> 16) & 1u)) >> 16;   // RNE
  return (ushort)u;
}

// pack two fp32 -> two bf16 (round-half-up) in one v_perm
__device__ __forceinline__ uint pack_bf2(float f0, float f1) {
  uint u0 = __float_as_uint(f0) + 0x8000u;
  uint u1 = __float_as_uint(f1) + 0x8000u;
  return __builtin_amdgcn_perm(u1, u0, 0x07060302u);
}

__device__ __forceinline__ float bf2f(ushort u) {
  return __uint_as_float(((uint)u) << 16);
}

// ---------------- K0: transpose x [B][CIN][HW] -> xTb [B][HW][CIN] bf16 ----------------
__global__ __launch_bounds__(256) void k_transpose_x(
    const float* __restrict__ x, ushort* __restrict__ xTb) {
  __shared__ float tile[64][65];
  int b = blockIdx.y;
  int p0 = blockIdx.x * 64;
  int tid = threadIdx.x;
  int j = tid & 63, cb = tid >> 6;
#pragma unroll
  for (int i = 0; i < 16; ++i) {
    int ci = cb * 16 + i;
    tile[ci][j] = x[((size_t)(b * CIN + ci)) * HW + p0 + j];
  }
  __syncthreads();
  int px = tid >> 2, ciq = tid & 3;
#pragma unroll
  for (int g = 0; g < 4; ++g) {
    int ci = ciq * 16 + g * 4;
    uint lo = pack_bf2(tile[ci + 0][px], tile[ci + 1][px]);
    uint hi = pack_bf2(tile[ci + 2][px], tile[ci + 3][px]);
    *(uint2*)&xTb[((size_t)b * HW + p0 + px) * 64 + ci] = make_uint2(lo, hi);
  }
}

// ---------------- weight prep ----------------
// w_offT[oc][k], k = kk*64+ci, oc padded to 32 (zeros) -- bf16 MFMA A for offset conv
// w_mf[co][h*288 + kk*32 + cil], ci = h*32+cil          -- bf16 MFMA A for deform
__global__ __launch_bounds__(256) void k_prep_w(
    const float* __restrict__ w_off, const float* __restrict__ w_dcn,
    ushort* __restrict__ w_offT, ushort* __restrict__ w_mf) {
  int i = blockIdx.x * 256 + threadIdx.x;
  if (i < 32 * KDIM) {
    int oc = i / KDIM, k = i - oc * KDIM;
    int kk = k >> 6, ci = k & 63;
    float v = (oc < OFFC) ? w_off[(oc * CIN + ci) * KK + kk] : 0.f;
    w_offT[i] = f2bf(v);
  } else if (i < 32 * KDIM + COUT * KDIM) {
    int jj = i - 32 * KDIM;
    int co = jj / KDIM, k = jj - co * KDIM;
    int h = k / KHALF, r = k - h * KHALF;
    int kk = r >> 5, cil = r & 31;
    int ci = h * 32 + cil;
    w_mf[jj] = f2bf(w_dcn[(co * CIN + ci) * KK + kk]);
  }
}

// ---------------- K1: offset conv as register-resident bf16 MFMA ----------------
__global__ __launch_bounds__(256) void k_offset_conv(
    const ushort* __restrict__ xTb, const ushort* __restrict__ w_offT,
    const float* __restrict__ bias, float* __restrict__ out) {
  int b = blockIdx.y;
  int wave = threadIdx.x >> 6, lane = threadIdx.x & 63;
  int row16 = lane & 15, quad = lane >> 4;
  int p = blockIdx.x * 64 + wave * 16 + row16;
  int ho = p / W, wo = p - ho * W;
  const ushort* xb = xTb + (size_t)b * HW * 64;

  short8 Bf[18];
#pragma unroll
  for (int ks = 0; ks < 18; ++ks) {
    int kk = ks >> 1;
    int ci0 = (ks & 1) * 32 + quad * 8;
    int kh = kk / 3, kw = kk - kh * 3;
    int yy = ho + kh - 1, xx = wo + kw - 1;
    bool valid = (yy >= 0) & (yy < H) & (xx >= 0) & (xx < W);
    short8 v = {0, 0, 0, 0, 0, 0, 0, 0};
    if (valid) v = *(const short8*)(xb + ((size_t)(yy * W + xx) << 6) + ci0);
    Bf[ks] = v;
  }
  floatx4 acc0 = {0.f, 0.f, 0.f, 0.f}, acc1 = acc0;
  const ushort* wa0 = w_offT + row16 * KDIM + quad * 8;
  const ushort* wa1 = w_offT + (16 + row16) * KDIM + quad * 8;
#pragma unroll
  for (int ks = 0; ks < 18; ++ks) {
    short8 A0 = *(const short8*)(wa0 + ks * 32);
    short8 A1 = *(const short8*)(wa1 + ks * 32);
    acc0 = __builtin_amdgcn_mfma_f32_16x16x32_bf16(A0, Bf[ks], acc0, 0, 0, 0);
    acc1 = __builtin_amdgcn_mfma_f32_16x16x32_bf16(A1, Bf[ks], acc1, 0, 0, 0);
  }
  float* ob = out + (size_t)b * OFFC * HW;
#pragma unroll
  for (int reg = 0; reg < 4; ++reg) {
    int oc = quad * 4 + reg;
    ob[(size_t)oc * HW + p] = acc0[reg] + bias[oc];
    int oc1 = 16 + oc;
    if (oc1 < OFFC) ob[(size_t)oc1 * HW + p] = acc1[reg] + bias[oc1];
  }
}

// ---------------- K3: deform conv (K-split bf16 MFMA) -> y bf16 + per-block BN partials ----------------
__global__ __launch_bounds__(256) void k_deform(
    const ushort* __restrict__ xTb, const float* __restrict__ off,
    const ushort* __restrict__ w_mf, ushort* __restrict__ y,
    float* __restrict__ psT) {
  __shared__ float4 s_w[KK][TP];
  __shared__ int4   s_i[KK][TP];
  __shared__ ushort samp[TP][KPAD2];

  int b = blockIdx.y;
  int p0 = blockIdx.x * TP;
  int bid = blockIdx.y * gridDim.x + blockIdx.x;
  int tid = threadIdx.x;
  const ushort* xb = xTb + (size_t)b * HW * 64;

  // ---- Phase A: bilinear metadata (288 tasks) ----
  for (int it = tid; it < KK * TP; it += 256) {
    int kk = it >> 5;
    int px = it & 31;
    int p = p0 + px;
    int ho = p / W, wo = p - ho * W;
    float dy = off[((size_t)b * OFFC + 2 * kk) * HW + p];
    float dx = off[((size_t)b * OFFC + 2 * kk + 1) * HW + p];
    float py = dy + (float)(ho - 1 + kk / 3);
    float pxx = dx + (float)(wo - 1 + kk % 3);
    float y0f = floorf(py), x0f = floorf(pxx);
    float wy1 = py - y0f, wx1 = pxx - x0f;
    int y0 = (int)y0f, x0 = (int)x0f;
    int y1 = y0 + 1, x1 = x0 + 1;
    float vy0 = (y0 >= 0 && y0 < H) ? 1.f : 0.f;
    float vy1 = (y1 >= 0 && y1 < H) ? 1.f : 0.f;
    float vx0 = (x0 >= 0 && x0 < W) ? 1.f : 0.f;
    float vx1 = (x1 >= 0 && x1 < W) ? 1.f : 0.f;
    int cy0 = min(max(y0, 0), H - 1), cy1 = min(max(y1, 0), H - 1);
    int cx0 = min(max(x0, 0), W - 1), cx1 = min(max(x1, 0), W - 1);
    s_w[kk][px] = make_float4((1.f - wy1) * (1.f - wx1) * vy0 * vx0,
                              (1.f - wy1) * wx1 * vy0 * vx1,
                              wy1 * (1.f - wx1) * vy1 * vx0,
                              wy1 * wx1 * vy1 * vx1);
    s_i[kk][px] = make_int4((cy0 * W + cx0) << 6, (cy0 * W + cx1) << 6,
                            (cy1 * W + cx0) << 6, (cy1 * W + cx1) << 6);
  }
  __syncthreads();

  int wave = tid >> 6, lane = tid & 63;
  int row16 = lane & 15, quad = lane >> 4;
  int koff = quad * 8;
  int co_base = wave * 32;
  const ushort* wa0 = w_mf + (size_t)(co_base + row16) * KDIM + koff;
  const ushort* wa1 = w_mf + (size_t)(co_base + 16 + row16) * KDIM + koff;

  floatx4 acc00 = {0.f, 0.f, 0.f, 0.f}, acc01 = acc00, acc10 = acc00, acc11 = acc00;

  for (int h = 0; h < 2; ++h) {
#pragma unroll
    for (int r = 0; r < 5; ++r) {
      int it = tid + r * 256;
      if (it < 1152) {
        int px = it / 36;
        int rem = it - px * 36;
        int kk = rem >> 2;
        int cig = rem & 3;
        int cil0 = cig * 8;
        int cio = h * 32 + cil0;
        float4 wv = s_w[kk][px];
        int4 iv = s_i[kk][px];
        ushort8 c0 = *(const ushort8*)(xb + iv.x + cio);
        ushort8 c1 = *(const ushort8*)(xb + iv.y + cio);
        ushort8 c2 = *(const ushort8*)(xb + iv.z + cio);
        ushort8 c3 = *(const ushort8*)(xb + iv.w + cio);
        uint pk[4];
#pragma unroll
        for (int g = 0; g < 4; ++g) {
          float r0 = wv.x * bf2f(c0[2 * g])     + wv.y * bf2f(c1[2 * g]) +
                     wv.z * bf2f(c2[2 * g])     + wv.w * bf2f(c3[2 * g]);
          float r1 = wv.x * bf2f(c0[2 * g + 1]) + wv.y * bf2f(c1[2 * g + 1]) +
                     wv.z * bf2f(c2[2 * g + 1]) + wv.w * bf2f(c3[2 * g + 1]);
          pk[g] = pack_bf2(r0, r1);
        }
        *(uint4*)&samp[px][kk * 32 + cil0] = make_uint4(pk[0], pk[1], pk[2], pk[3]);
      }
    }
    __syncthreads();

    const ushort* sb0 = &samp[row16][koff];
    const ushort* sb1 = &samp[16 + row16][koff];
    const ushort* a0 = wa0 + h * KHALF;
    const ushort* a1 = wa1 + h * KHALF;
#pragma unroll
    for (int ks = 0; ks < 9; ++ks) {
      short8 A0 = *(const short8*)(a0 + ks * 32);
      short8 A1 = *(const short8*)(a1 + ks * 32);
      short8 B0 = *(const short8*)(sb0 + ks * 32);
      short8 B1 = *(const short8*)(sb1 + ks * 32);
      acc00 = __builtin_amdgcn_mfma_f32_16x16x32_bf16(A0, B0, acc00, 0, 0, 0);
      acc01 = __builtin_amdgcn_mfma_f32_16x16x32_bf16(A0, B1, acc01, 0, 0, 0);
      acc10 = __builtin_amdgcn_mfma_f32_16x16x32_bf16(A1, B0, acc10, 0, 0, 0);
      acc11 = __builtin_amdgcn_mfma_f32_16x16x32_bf16(A1, B1, acc11, 0, 0, 0);
    }
    if (h == 0) __syncthreads();
  }

  // ---- epilogue: y store (bf16) + per-block BN partials (no atomics) ----
  ushort* yb = y + (size_t)b * COUT * HW + p0;
#pragma unroll
  for (int reg = 0; reg < 4; ++reg) {
    int r0 = quad * 4 + reg;
    yb[(size_t)(co_base + r0) * HW + row16]      = f2bf(acc00[reg]);
    yb[(size_t)(co_base + r0) * HW + 16 + row16] = f2bf(acc01[reg]);
    yb[(size_t)(co_base + 16 + r0) * HW + row16]      = f2bf(acc10[reg]);
    yb[(size_t)(co_base + 16 + r0) * HW + 16 + row16] = f2bf(acc11[reg]);
  }
#pragma unroll
  for (int reg = 0; reg < 4; ++reg) {
    float s0 = acc00[reg] + acc01[reg];
    float q0 = acc00[reg] * acc00[reg] + acc01[reg] * acc01[reg];
    float s1 = acc10[reg] + acc11[reg];
    float q1 = acc10[reg] * acc10[reg] + acc11[reg] * acc11[reg];
#pragma unroll
    for (int m = 1; m < 16; m <<= 1) {
      s0 += __shfl_xor(s0, m, 64);
      q0 += __shfl_xor(q0, m, 64);
      s1 += __shfl_xor(s1, m, 64);
      q1 += __shfl_xor(q1, m, 64);
    }
    if (row16 == 0) {
      int c0 = co_base + quad * 4 + reg;
      int c1 = c0 + 16;
      psT[(size_t)c0 * NB + bid]         = s0;
      psT[(size_t)(128 + c0) * NB + bid] = q0;
      psT[(size_t)c1 * NB + bid]         = s1;
      psT[(size_t)(128 + c1) * NB + bid] = q1;
    }
  }
}

// ---------------- K4: reduce per-block partials -> stats[256] ----------------
__global__ __launch_bounds__(256) void k_reduce(const float* __restrict__ psT,
                                                float* __restrict__ stats) {
  int j = blockIdx.x;      // 0..255: 0..127 sums, 128..255 sumsq
  int tid = threadIdx.x;
  float s = 0.f;
  for (int i = tid; i < NB; i += 256) s += psT[(size_t)j * NB + i];
#pragma unroll
  for (int o = 32; o > 0; o >>= 1) s += __shfl_down(s, o, 64);
  __shared__ float ls[4];
  int lane = tid & 63, wid = tid >> 6;
  if (lane == 0) ls[wid] = s;
  __syncthreads();
  if (tid == 0) stats[j] = ls[0] + ls[1] + ls[2] + ls[3];
}

// ---------------- K5: finalize stats + normalize + ReLU (y bf16 -> out fp32) ----------------
__global__ __launch_bounds__(256) void k_norm(const ushort* __restrict__ y,
                                              const float* __restrict__ stats,
                                              const float* __restrict__ gamma,
                                              const float* __restrict__ beta,
                                              float* __restrict__ out) {
  int i4 = blockIdx.x * 256 + threadIdx.x;
  const int total4 = BATCH * COUT * HW / 4;
  if (i4 >= total4) return;
  size_t i = (size_t)i4 * 4;
  int c = (int)((i / HW) & (COUT - 1));
  const float N = (float)(BATCH * HW);
  float m = stats[c] / N;
  float var = stats[COUT + c] / N - m * m;
  float r = rsqrtf(var + EPS);
  float g = gamma[c], bt = beta[c];
  ushort8 v8 = *(const ushort8*)&y[i];   // reads 8? no -- use uint2 (4 elems)
  // NOTE: we only need 4 elems; load uint2
  uint2 u = *(const uint2*)&y[i];
  float4 v = make_float4(bf2f((ushort)(u.x & 0xFFFF)), bf2f((ushort)(u.x >> 16)),
                         bf2f((ushort)(u.y & 0xFFFF)), bf2f((ushort)(u.y >> 16)));
  (void)v8;
  v.x = fmaxf(0.f, (v.x - m) * r * g + bt);
  v.y = fmaxf(0.f, (v.y - m) * r * g + bt);
  v.z = fmaxf(0.f, (v.z - m) * r * g + bt);
  v.w = fmaxf(0.f, (v.w - m) * r * g + bt);
  *(float4*)&out[i] = v;
}

extern "C" void kernel_launch(void* const* d_in, const int* in_sizes, int n_in,
                              void* d_out, int out_size, void* d_ws, size_t ws_size,
                              hipStream_t stream) {
  const float* x     = (const float*)d_in[0];
  const float* w_off = (const float*)d_in[1];
  const float* b_off = (const float*)d_in[2];
  const float* w_dcn = (const float*)d_in[3];
  // d_in[4] = b_dcn: cancels exactly through batch-norm
  const float* gamma = (const float*)d_in[5];
  const float* beta  = (const float*)d_in[6];
  float* out = (float*)d_out;

  float* ws = (float*)d_ws;
  float*  off_buf = ws;                               //  1,806,336 floats
  float*  psT     = off_buf + 1806336;                //    802,816 floats
  float*  stats   = psT + 802816;                     //        256
  ushort* xTb     = (ushort*)(stats + 256);           //  6,422,528 ushorts
  ushort* w_mf    = xTb + 6422528;                    //     73,728
  ushort* w_offT  = w_mf + 73728;                     //     18,432
  ushort* y_bf    = w_offT + 18432;                   // 12,845,056 ushorts
  // total ~49 MB

  k_transpose_x<<<dim3(HW / 64, BATCH), 256, 0, stream>>>(x, xTb);
  k_prep_w<<<(32 * KDIM + COUT * KDIM + 255) / 256, 256, 0, stream>>>(w_off, w_dcn, w_offT, w_mf);
  k_offset_conv<<<dim3(HW / 64, BATCH), 256, 0, stream>>>(xTb, w_offT, b_off, off_buf);
  k_deform<<<dim3(HW / TP, BATCH), 256, 0, stream>>>(xTb, off_buf, w_mf, y_bf, psT);
  k_reduce<<<256, 256, 0, stream>>>(psT, stats);
  k_norm<<<(BATCH * COUT * HW / 4 + 255) / 256, 256, 0, stream>>>(y_bf, stats, gamma, beta, out);
}